// Round 20
// baseline (230.118 us; speedup 1.0000x reference)
//
#include <hip/hip_runtime.h>
#include <math.h>

// x: [8][64][256][256] f32 ; w1/w2: [2][32][32][32] f32 (re,im separate)
// Pipeline:
//   K1 w_fwd : DFT_W via MFMA, A-frags loaded DIRECT from global (no LDS stage),
//              x bf16 (RNE in regs), E bf16 hi+lo -> mixW -> Yw[c][h][64]
//   K2 h_fwd : DFT_H (folded, Chebyshev)  -> Z [bg,kh,o][128]
//   K3 h_mix2: mixH                       -> Z2[c][kh][128]
//   K4 h_inv2: IDFT_H (mirror)            -> YH[c][h][64] (reuses Yw region)
//   K5 w_inv2: IDFT_W (mirror)            -> out (all-float4 stores via shfl)
#define PI2_256 0.0245436926061702596754894014318f  // 2*pi/256

typedef __attribute__((ext_vector_type(8))) short short8;   // 8 bf16 (4 VGPRs)
typedef __attribute__((ext_vector_type(4))) float f32x4;

static __device__ __forceinline__ unsigned short f2bf(float f) {
    unsigned int u = __float_as_uint(f);
    u = (u + 0x7FFFu + ((u >> 16) & 1u)) >> 16;              // RNE
    return (unsigned short)u;
}
static __device__ __forceinline__ float bf2f(unsigned short h) {
    return __uint_as_float(((unsigned int)h) << 16);
}
static __device__ __forceinline__ short8 cvt8(const float4 a, const float4 b) {
    short8 r;
    r[0] = (short)f2bf(a.x); r[1] = (short)f2bf(a.y);
    r[2] = (short)f2bf(a.z); r[3] = (short)f2bf(a.w);
    r[4] = (short)f2bf(b.x); r[5] = (short)f2bf(b.y);
    r[6] = (short)f2bf(b.z); r[7] = (short)f2bf(b.w);
    return r;
}

// ---------------------------------------------------------------------------
__global__ __launch_bounds__(256) void init_tab(float* __restrict__ tc, float* __restrict__ ts) {
    int idx = blockIdx.x * 256 + threadIdx.x;   // 0..8191
    int k = idx >> 8, n = idx & 255;            // k < 32
    int m = (k * n) & 255;
    float s, c;
    sincosf(PI2_256 * (float)m, &s, &c);
    tc[idx] = c;
    ts[idx] = s;
}

// Et (transposed DFT matrix) in bf16 hi/lo: Et[n][w], n<32: cos(2pi n w/256),
// n in 32..63: -sin(2pi (n-32) w/256).
__global__ __launch_bounds__(256) void init_et(unsigned short* __restrict__ Eth,
                                               unsigned short* __restrict__ Etl) {
    int idx = blockIdx.x * 256 + threadIdx.x;   // 0..16383
    int n = idx >> 8, w = idx & 255;
    int k = n & 31;
    int m = (k * w) & 255;
    float s, c;
    sincosf(PI2_256 * (float)m, &s, &c);
    float v = (n < 32) ? c : -s;
    unsigned short h = f2bf(v);
    Eth[idx] = h;
    Etl[idx] = f2bf(v - bf2f(h));
}

// ---------------------------------------------------------------------------
// K1: per block = (b,g,row-pair). A-fragments direct from global (each wave
// reads the full tile; L2 absorbs the 4x redundancy). No LDS staging, ONE
// barrier. GEMM X = x @ E (bf16, E split hi+lo), then phase B mixW.
// ---------------------------------------------------------------------------
__global__ __launch_bounds__(256) void w_fwd(const float* __restrict__ x,
                                             const float* __restrict__ w2r,
                                             const float* __restrict__ w2i,
                                             const unsigned short* __restrict__ Eth,
                                             const unsigned short* __restrict__ Etl,
                                             float* __restrict__ Yw) {
    __shared__ float XrL[2][32 * 36], XiL[2][32 * 36];      // 18.4 KB

    const int bid = blockIdx.x;      // 2048 blocks
    const int jr  = bid & 127;       // row pair
    const int g   = (bid >> 7) & 1;
    const int b   = bid >> 8;
    const int t   = threadIdx.x;

    const size_t chan0 = (size_t)(b * 64 + g * 32);

    const int l  = t & 63, wv = t >> 6;
    const int lr = l & 15, lk = (l >> 4) * 8;

    const unsigned short* bhp = Eth + (size_t)(wv * 16 + lr) * 256 + lk;
    const unsigned short* blp = Etl + (size_t)(wv * 16 + lr) * 256 + lk;
    const float* xp0 = x + (chan0 + lr) * 65536 + lk;        // + xrow*256 + ks*32
    const float* xp1 = x + (chan0 + 16 + lr) * 65536 + lk;
    const int col   = wv * 16 + lr;
    const int rbase = (l >> 4) * 4;

    #pragma unroll
    for (int rr = 0; rr < 2; ++rr) {
        const size_t ro = (size_t)(jr * 2 + rr) * 256;
        f32x4 acc0 = {0.f, 0.f, 0.f, 0.f};
        f32x4 acc1 = {0.f, 0.f, 0.f, 0.f};
        #pragma unroll
        for (int ks = 0; ks < 8; ++ks) {
            const int off = ks * 32;
            const float4 u00 = *(const float4*)(xp0 + ro + off);
            const float4 u01 = *(const float4*)(xp0 + ro + off + 4);
            const float4 u10 = *(const float4*)(xp1 + ro + off);
            const float4 u11 = *(const float4*)(xp1 + ro + off + 4);
            const short8 bh = *(const short8*)(bhp + off);
            const short8 bl = *(const short8*)(blp + off);
            const short8 a0 = cvt8(u00, u01);
            const short8 a1 = cvt8(u10, u11);
            acc0 = __builtin_amdgcn_mfma_f32_16x16x32_bf16(a0, bh, acc0, 0, 0, 0);
            acc1 = __builtin_amdgcn_mfma_f32_16x16x32_bf16(a1, bh, acc1, 0, 0, 0);
            acc0 = __builtin_amdgcn_mfma_f32_16x16x32_bf16(a0, bl, acc0, 0, 0, 0);
            acc1 = __builtin_amdgcn_mfma_f32_16x16x32_bf16(a1, bl, acc1, 0, 0, 0);
        }
        // C/D: col = wv*16 + (lane&15), row = (lane>>4)*4 + reg
        #pragma unroll
        for (int r = 0; r < 4; ++r) {
            const int row0 = rbase + r;
            const int row1 = 16 + rbase + r;
            const float v0 = acc0[r], v1 = acc1[r];
            if (col < 32) {
                XrL[rr][row0 * 36 + col] = v0;
                XrL[rr][row1 * 36 + col] = v1;
            } else {
                XiL[rr][row0 * 36 + col - 32] = v0;
                XiL[rr][row1 * 36 + col - 32] = v1;
            }
        }
    }
    __syncthreads();

    // ---- phase B: mixW for BOTH rows per weight load; scale folded ----
    {
        const int kq = t & 7, o = t >> 3;
        const int k4 = kq * 4;
        float4 ar0 = {0,0,0,0}, ai0 = {0,0,0,0};
        float4 ar1 = {0,0,0,0}, ai1 = {0,0,0,0};
        const float* wrb = w2r + (size_t)g * 32768 + o * 32 + k4;   // + i*1024
        const float* wib = w2i + (size_t)g * 32768 + o * 32 + k4;
        for (int i = 0; i < 32; ++i) {
            const float4 wr  = *(const float4*)(wrb + i * 1024);
            const float4 wi  = *(const float4*)(wib + i * 1024);
            const float4 xr0 = *(const float4*)(&XrL[0][i * 36 + k4]);
            const float4 xi0 = *(const float4*)(&XiL[0][i * 36 + k4]);
            const float4 xr1 = *(const float4*)(&XrL[1][i * 36 + k4]);
            const float4 xi1 = *(const float4*)(&XiL[1][i * 36 + k4]);
            ar0.x += xr0.x * wr.x - xi0.x * wi.x;  ai0.x += xr0.x * wi.x + xi0.x * wr.x;
            ar0.y += xr0.y * wr.y - xi0.y * wi.y;  ai0.y += xr0.y * wi.y + xi0.y * wr.y;
            ar0.z += xr0.z * wr.z - xi0.z * wi.z;  ai0.z += xr0.z * wi.z + xi0.z * wr.z;
            ar0.w += xr0.w * wr.w - xi0.w * wi.w;  ai0.w += xr0.w * wi.w + xi0.w * wr.w;
            ar1.x += xr1.x * wr.x - xi1.x * wi.x;  ai1.x += xr1.x * wi.x + xi1.x * wr.x;
            ar1.y += xr1.y * wr.y - xi1.y * wi.y;  ai1.y += xr1.y * wi.y + xi1.y * wr.y;
            ar1.z += xr1.z * wr.z - xi1.z * wi.z;  ai1.z += xr1.z * wi.z + xi1.z * wr.z;
            ar1.w += xr1.w * wr.w - xi1.w * wi.w;  ai1.w += xr1.w * wi.w + xi1.w * wr.w;
        }
        const float s2 = 2.f / 256.f, s1 = 1.f / 256.f;
        const float s0 = (k4 == 0) ? s1 : s2;
        float* dst0 = Yw + (size_t)((b * 2 + g) * 32 + o) * 16384
                         + (size_t)(jr * 2) * 64 + k4;
        *(float4*)(dst0)           = make_float4(ar0.x * s0, ar0.y * s2, ar0.z * s2, ar0.w * s2);
        *(float4*)(dst0 + 32)      = make_float4(ai0.x * s0, ai0.y * s2, ai0.z * s2, ai0.w * s2);
        *(float4*)(dst0 + 64)      = make_float4(ar1.x * s0, ar1.y * s2, ar1.z * s2, ar1.w * s2);
        *(float4*)(dst0 + 64 + 32) = make_float4(ai1.x * s0, ai1.y * s2, ai1.z * s2, ai1.w * s2);
    }
}

// ---------------------------------------------------------------------------
// K2: folded DFT_H per channel c. Chebyshev with exact LDS-derived seeds.
// ---------------------------------------------------------------------------
__global__ __launch_bounds__(256) void h_fwd(const float* __restrict__ Yw,
                                             float* __restrict__ Z) {
    __shared__ float YL[256 * 64];   // 64 KB
    __shared__ float kC[32], kS[32];
    const int bid = blockIdx.x;      // (b*2+g)*32 + o
    const int t = threadIdx.x;
    if (t < 32) {
        float s, c; sincosf(PI2_256 * (float)t, &s, &c);
        kC[t] = c; kS[t] = s;
    }
    {
        const float* src = Yw + (size_t)bid * 16384;
        #pragma unroll
        for (int r = 0; r < 16; ++r) {
            const int f = t + r * 256;
            *(float4*)(YL + f * 4) = *(const float4*)(src + f * 4);
        }
    }
    __syncthreads();

    const int hs = t & 1, kg = (t >> 1) & 7, sp = t >> 4;  // slots 4sp..4sp+3
    const int hb = hs * 64;
    const float sgn = (kg & 1) ? -1.f : 1.f;
    const float4 y0q   = *(const float4*)(YL + sp * 4);
    const float4 y128q = *(const float4*)(YL + 128 * 64 + sp * 4);

    float cA[4], sA[4], cB[4], sB[4], t2[4];
    float xr[4][4], xi[4][4];
    #pragma unroll
    for (int kk = 0; kk < 4; ++kk) {
        const int k = kg + 8 * kk;
        const float cd = kC[k], sd = kS[k];
        t2[kk] = 2.f * cd;
        float cA0, sA0;
        if (hs == 0) { cA0 = 1.f; sA0 = 0.f; }
        else {
            const int km = k & 3;
            cA0 = (km == 0) ? 1.f : (km == 2) ? -1.f : 0.f;
            sA0 = (km == 1) ? 1.f : (km == 3) ? -1.f : 0.f;
        }
        cA[kk] = cA0; sA[kk] = sA0;
        cB[kk] = cA0 * cd + sA0 * sd;
        sB[kk] = sA0 * cd - cA0 * sd;
        #pragma unroll
        for (int j = 0; j < 4; ++j) {
            xr[kk][j] = (hs == 0) ? (sgn * (&y128q.x)[j] - (&y0q.x)[j]) : 0.f;
            xi[kk][j] = 0.f;
        }
    }
    for (int h = hb; h < hb + 64; ++h) {
        const float4 aq = *(const float4*)(YL + h * 64 + sp * 4);
        const float4 mq = *(const float4*)(YL + ((256 - h) & 255) * 64 + sp * 4);
        float ye[4], yo[4];
        #pragma unroll
        for (int j = 0; j < 4; ++j) {
            ye[j] = (&aq.x)[j] + (&mq.x)[j];
            yo[j] = (&aq.x)[j] - (&mq.x)[j];
        }
        #pragma unroll
        for (int kk = 0; kk < 4; ++kk) {
            #pragma unroll
            for (int j = 0; j < 4; ++j) {
                xr[kk][j] += ye[j] * cA[kk];
                xi[kk][j] -= yo[j] * sA[kk];
            }
            const float cn = t2[kk] * cA[kk] - cB[kk]; cB[kk] = cA[kk]; cA[kk] = cn;
            const float sn = t2[kk] * sA[kk] - sB[kk]; sB[kk] = sA[kk]; sA[kk] = sn;
        }
    }
    #pragma unroll
    for (int kk = 0; kk < 4; ++kk)
        #pragma unroll
        for (int j = 0; j < 4; ++j) {
            xr[kk][j] += __shfl_xor(xr[kk][j], 1);
            xi[kk][j] += __shfl_xor(xi[kk][j], 1);
        }
    if (hs == 0) {
        const int o = bid & 31, bg = bid >> 5;
        #pragma unroll
        for (int kk = 0; kk < 4; ++kk) {
            const int k = kg + 8 * kk;
            const size_t zi_ = (((size_t)bg * 32 + k) * 32 + o) * 128 + sp * 4;
            *(float4*)(Z + zi_)      = make_float4(xr[kk][0], xr[kk][1], xr[kk][2], xr[kk][3]);
            *(float4*)(Z + zi_ + 64) = make_float4(xi[kk][0], xi[kk][1], xi[kk][2], xi[kk][3]);
        }
    }
}

// ---------------------------------------------------------------------------
// K3: mixH per (b,g,kh); H-ortho scale folded. Z2: [(bg*32+o)*32+kh][128]
// ---------------------------------------------------------------------------
__global__ __launch_bounds__(256) void h_mix2(const float* __restrict__ Z,
                                              const float* __restrict__ w1r,
                                              const float* __restrict__ w1i,
                                              float* __restrict__ Z2) {
    __shared__ float ZL[32 * 128];          // [i][128] 16 KB
    __shared__ float WrL[1024], WiL[1024];  // [i*32+o] 8 KB
    const int bid = blockIdx.x;             // bg*32 + kh
    const int kh = bid & 31, bg = bid >> 5;
    const int g = bg & 1;
    const int t = threadIdx.x;
    {
        const float* src = Z + (size_t)bid * 4096;
        #pragma unroll
        for (int r = 0; r < 4; ++r) {
            const int f = t + r * 256;
            *(float4*)(ZL + f * 4) = *(const float4*)(src + f * 4);
        }
        #pragma unroll
        for (int r = 0; r < 4; ++r) {
            const int idx = t + r * 256;    // i = idx>>5, o = idx&31
            const int gidx = g * 32768 + (idx >> 5) * 1024 + (idx & 31) * 32 + kh;
            WrL[idx] = w1r[gidx];
            WiL[idx] = w1i[gidx];
        }
    }
    __syncthreads();

    const int s = t & 63, og = t >> 6;      // o = og*8 + m
    float accr[8], acci[8];
    #pragma unroll
    for (int m = 0; m < 8; ++m) { accr[m] = 0.f; acci[m] = 0.f; }
    for (int i = 0; i < 32; ++i) {
        const float zr = ZL[i * 128 + s];
        const float zi = ZL[i * 128 + 64 + s];
        #pragma unroll
        for (int m = 0; m < 8; ++m) {
            const int o = og * 8 + m;
            const float wr = WrL[i * 32 + o];
            const float wi = WiL[i * 32 + o];
            accr[m] += zr * wr - zi * wi;
            acci[m] += zr * wi + zi * wr;
        }
    }
    const float sck = (kh == 0) ? (1.f / 256.f) : (2.f / 256.f);
    #pragma unroll
    for (int m = 0; m < 8; ++m) {
        const int o = og * 8 + m;
        const size_t zo = ((size_t)(bg * 32 + o) * 32 + kh) * 128 + s;
        Z2[zo]      = accr[m] * sck;
        Z2[zo + 64] = acci[m] * sck;
    }
}

// ---------------------------------------------------------------------------
// K4: IDFT_H (mirror, Nyquist) per channel c. Trig staged in LDS.
// ---------------------------------------------------------------------------
__global__ __launch_bounds__(256) void h_inv2(const float* __restrict__ Z2,
                                              const float* __restrict__ tc,
                                              const float* __restrict__ ts,
                                              float* __restrict__ YHg) {
    __shared__ float ZL[32 * 128];                  // 16 KB
    __shared__ float TcL[32 * 128], TsL[32 * 128];  // 16+16 KB (lower-half trig)
    const int bid = blockIdx.x;                     // channel c
    const int t = threadIdx.x;
    {
        const float* src = Z2 + (size_t)bid * 4096;
        #pragma unroll
        for (int r = 0; r < 4; ++r) {
            const int f = t + r * 256;
            *(float4*)(ZL + f * 4) = *(const float4*)(src + f * 4);
        }
        #pragma unroll
        for (int r = 0; r < 4; ++r) {
            const int q = t + r * 256;              // 0..1023
            const int k = q >> 5, hq = q & 31;
            *(float4*)(TcL + k * 128 + hq * 4) = *(const float4*)(tc + (size_t)k * 256 + hq * 4);
            *(float4*)(TsL + k * 128 + hq * 4) = *(const float4*)(ts + (size_t)k * 256 + hq * 4);
        }
    }
    __syncthreads();

    const int s = t & 63, hg = t >> 6;              // hg 0..3
    float zr[32], zi[32];
    #pragma unroll
    for (int k = 0; k < 32; ++k) {
        zr[k] = ZL[k * 128 + s];
        zi[k] = ZL[k * 128 + 64 + s];
    }
    float* dst = YHg + (size_t)bid * 16384;
    #pragma unroll
    for (int jq = 0; jq < 8; ++jq) {
        const int h0 = hg * 32 + jq * 4;            // 0..124
        float sC[4] = {0, 0, 0, 0}, sS[4] = {0, 0, 0, 0};
        #pragma unroll
        for (int k = 0; k < 32; ++k) {
            const float4 c4 = *(const float4*)(TcL + k * 128 + h0);  // wave-uniform
            const float4 s4 = *(const float4*)(TsL + k * 128 + h0);
            sC[0] += zr[k] * c4.x;  sS[0] += zi[k] * s4.x;
            sC[1] += zr[k] * c4.y;  sS[1] += zi[k] * s4.y;
            sC[2] += zr[k] * c4.z;  sS[2] += zi[k] * s4.z;
            sC[3] += zr[k] * c4.w;  sS[3] += zi[k] * s4.w;
        }
        #pragma unroll
        for (int jj = 0; jj < 4; ++jj) {
            const int h = h0 + jj;
            dst[h * 64 + s] = sC[jj] - sS[jj];
            if (h > 0) dst[(256 - h) * 64 + s] = sC[jj] + sS[jj];
        }
    }
    if (hg == 0) {                                  // Nyquist row h = 128
        float ny = 0.f;
        #pragma unroll
        for (int k = 0; k < 32; ++k) ny += (k & 1) ? -zr[k] : zr[k];
        dst[128 * 64 + s] = ny;
    }
}

// ---------------------------------------------------------------------------
// K5: IDFT_W (mirror, Nyquist). block = (c, hb): 32 h-rows. Trig in LDS.
// Mirror half assembled via width-32 shuffles -> ALL stores are float4.
// ---------------------------------------------------------------------------
__global__ __launch_bounds__(256) void w_inv2(const float* __restrict__ YHg,
                                              const float* __restrict__ tc,
                                              const float* __restrict__ ts,
                                              float* __restrict__ out) {
    __shared__ float YL[32 * 64];                   // 8 KB  [hl][64]
    __shared__ float TcL[32 * 128], TsL[32 * 128];  // 32 KB (lower-half trig)
    const int bid = blockIdx.x;
    const int hb = bid & 7, c = bid >> 3;
    const int t = threadIdx.x;
    {
        const float* src = YHg + (size_t)c * 16384 + hb * 2048;
        #pragma unroll
        for (int r = 0; r < 2; ++r) {
            const int f = t + r * 256;
            *(float4*)(YL + f * 4) = *(const float4*)(src + f * 4);
        }
        #pragma unroll
        for (int r = 0; r < 4; ++r) {
            const int q = t + r * 256;              // 0..1023
            const int k = q >> 5, wq_ = q & 31;
            *(float4*)(TcL + k * 128 + wq_ * 4) = *(const float4*)(tc + (size_t)k * 256 + wq_ * 4);
            *(float4*)(TsL + k * 128 + wq_ * 4) = *(const float4*)(ts + (size_t)k * 256 + wq_ * 4);
        }
    }
    __syncthreads();

    const int wq = t & 31, hh = t >> 5;             // 4 h-rows per thread
    const int w0 = wq * 4;
    float* outp = out + (size_t)c * 65536;

    float sC[4][4], sS[4][4];                       // [j][w-lane]
    float nyA[4];                                   // Nyquist accum (uniform per row)
    #pragma unroll
    for (int j = 0; j < 4; ++j) {
        nyA[j] = 0.f;
        #pragma unroll
        for (int jj = 0; jj < 4; ++jj) { sC[j][jj] = 0.f; sS[j][jj] = 0.f; }
    }

    for (int k = 0; k < 32; ++k) {
        const float4 c4 = *(const float4*)(TcL + k * 128 + w0);
        const float4 s4 = *(const float4*)(TsL + k * 128 + w0);
        const float sk = (k & 1) ? -1.f : 1.f;
        #pragma unroll
        for (int j = 0; j < 4; ++j) {
            const int hl = hh * 4 + j;
            const float R = YL[hl * 64 + k];
            const float I = YL[hl * 64 + 32 + k];
            nyA[j] += sk * R;
            sC[j][0] += R * c4.x;  sS[j][0] += I * s4.x;
            sC[j][1] += R * c4.y;  sS[j][1] += I * s4.y;
            sC[j][2] += R * c4.z;  sS[j][2] += I * s4.z;
            sC[j][3] += R * c4.w;  sS[j][3] += I * s4.w;
        }
    }
    #pragma unroll
    for (int j = 0; j < 4; ++j) {
        const int h = hb * 32 + hh * 4 + j;
        *(float4*)(outp + (size_t)h * 256 + w0) =
            make_float4(sC[j][0] - sS[j][0], sC[j][1] - sS[j][1],
                        sC[j][2] - sS[j][2], sC[j][3] - sS[j][3]);
        const float p0 = sC[j][0] + sS[j][0];
        const float p1 = sC[j][1] + sS[j][1];
        const float p2 = sC[j][2] + sS[j][2];
        const float p3 = sC[j][3] + sS[j][3];
        const float m0s = __shfl(p0, 32 - wq, 32);
        const float m0  = (wq == 0) ? nyA[j] : m0s;
        const float m1  = __shfl(p3, 31 - wq, 32);
        const float m2  = __shfl(p2, 31 - wq, 32);
        const float m3  = __shfl(p1, 31 - wq, 32);
        *(float4*)(outp + (size_t)h * 256 + 128 + w0) = make_float4(m0, m1, m2, m3);
    }
}

// ---------------------------------------------------------------------------
extern "C" void kernel_launch(void* const* d_in, const int* in_sizes, int n_in,
                              void* d_out, int out_size, void* d_ws, size_t ws_size,
                              hipStream_t stream) {
    const float* x   = (const float*)d_in[0];
    const float* w1r = (const float*)d_in[1];
    const float* w1i = (const float*)d_in[2];
    const float* w2r = (const float*)d_in[3];
    const float* w2i = (const float*)d_in[4];
    float* out = (float*)d_out;
    float* ws  = (float*)d_ws;

    float* tc = ws;                    //  8192 floats
    float* ts = ws + 8192;             //  8192 floats
    float* Yw = ws + 16384;            //  8,388,608 floats (33.5 MB) — reused as YHg
    float* Z  = Yw + 8388608;          //  2,097,152 floats ( 8.4 MB)
    float* Z2 = Z + 2097152;           //  2,097,152 floats ( 8.4 MB)
    unsigned short* Eth = (unsigned short*)(Z2 + 2097152);   // 16384 bf16 (32 KB)
    unsigned short* Etl = Eth + 16384;                       // 16384 bf16 (32 KB)

    init_tab<<<32, 256, 0, stream>>>(tc, ts);
    init_et<<<64, 256, 0, stream>>>(Eth, Etl);
    w_fwd<<<2048, 256, 0, stream>>>(x, w2r, w2i, Eth, Etl, Yw);
    h_fwd<<<512, 256, 0, stream>>>(Yw, Z);
    h_mix2<<<512, 256, 0, stream>>>(Z, w1r, w1i, Z2);
    h_inv2<<<512, 256, 0, stream>>>(Z2, tc, ts, Yw);   // Yw region reused as YH
    w_inv2<<<4096, 256, 0, stream>>>(Yw, tc, ts, out);
}

// Round 21
// 184.076 us; speedup vs baseline: 1.2501x; 1.2501x over previous
//
#include <hip/hip_runtime.h>
#include <math.h>

// x: [8][64][256][256] f32 ; w1/w2: [2][32][32][32] f32 (re,im separate)
// Pipeline:
//   K1 w_fwd : DFT_W via MFMA, x bf16, E bf16 hi+lo -> Yw[c][h][64]  (R17 best)
//   K2 h_fwd : DFT_H (folded, Chebyshev), SPLIT: block=(c,slot-half) -> Z
//   K3 h_mix2: mixH                       -> Z2[c][kh][128]
//   K4 h_inv2: IDFT_H (mirror)            -> YH[c][h][64] (reuses Yw region)
//   K5 w_inv2: IDFT_W (mirror)            -> out (all-float4 stores via shfl)
#define PI2_256 0.0245436926061702596754894014318f  // 2*pi/256
#define AS 264   // padded bf16 tile stride: 528B = 16B mod 128B -> conflict-free b128

typedef __attribute__((ext_vector_type(8))) short short8;   // 8 bf16 (4 VGPRs)
typedef __attribute__((ext_vector_type(4))) float f32x4;

static __device__ __forceinline__ unsigned short f2bf(float f) {
    unsigned int u = __float_as_uint(f);
    u = (u + 0x7FFFu + ((u >> 16) & 1u)) >> 16;              // RNE
    return (unsigned short)u;
}
static __device__ __forceinline__ float bf2f(unsigned short h) {
    return __uint_as_float(((unsigned int)h) << 16);
}

// ---------------------------------------------------------------------------
__global__ __launch_bounds__(256) void init_tab(float* __restrict__ tc, float* __restrict__ ts) {
    int idx = blockIdx.x * 256 + threadIdx.x;   // 0..8191
    int k = idx >> 8, n = idx & 255;            // k < 32
    int m = (k * n) & 255;
    float s, c;
    sincosf(PI2_256 * (float)m, &s, &c);
    tc[idx] = c;
    ts[idx] = s;
}

// Et (transposed DFT matrix) in bf16 hi/lo: Et[n][w], n<32: cos(2pi n w/256),
// n in 32..63: -sin(2pi (n-32) w/256).
__global__ __launch_bounds__(256) void init_et(unsigned short* __restrict__ Eth,
                                               unsigned short* __restrict__ Etl) {
    int idx = blockIdx.x * 256 + threadIdx.x;   // 0..16383
    int n = idx >> 8, w = idx & 255;
    int k = n & 31;
    int m = (k * w) & 255;
    float s, c;
    sincosf(PI2_256 * (float)m, &s, &c);
    float v = (n < 32) ? c : -s;
    unsigned short h = f2bf(v);
    Eth[idx] = h;
    Etl[idx] = f2bf(v - bf2f(h));
}

// ---------------------------------------------------------------------------
// K1: per block = (b,g,row-pair). Per row: stage x->bf16 (padded) -> MFMA
// GEMM X = x @ E (x_hi * (E_hi + E_lo), fp32 acc) -> XrL[rr]. One phase B.
// ---------------------------------------------------------------------------
__global__ __launch_bounds__(256) void w_fwd(const float* __restrict__ x,
                                             const float* __restrict__ w2r,
                                             const float* __restrict__ w2i,
                                             const unsigned short* __restrict__ Eth,
                                             const unsigned short* __restrict__ Etl,
                                             float* __restrict__ Yw) {
    __shared__ __attribute__((aligned(16))) unsigned short Ah[32 * AS];   // 16.5 KB
    __shared__ float XrL[2][32 * 36], XiL[2][32 * 36];                    // 18.4 KB

    const int bid = blockIdx.x;      // 2048 blocks
    const int jr  = bid & 127;       // row pair
    const int g   = (bid >> 7) & 1;
    const int b   = bid >> 8;
    const int t   = threadIdx.x;

    const size_t chan0 = (size_t)(b * 64 + g * 32);

    for (int rr = 0; rr < 2; ++rr) {
        const int xrow = jr * 2 + rr;
        const size_t base = (chan0 * 256 + xrow) * 256;    // + i*65536 + w

        // ---- stage + convert to bf16 (padded stride) ----
        {
            const int wq = t & 63, i0 = t >> 6;
            #pragma unroll
            for (int r = 0; r < 8; ++r) {
                const int i = i0 + r * 4;
                const float4 v = *(const float4*)(x + base + (size_t)i * 65536 + wq * 4);
                ushort4 hq;
                hq.x = f2bf(v.x);
                hq.y = f2bf(v.y);
                hq.z = f2bf(v.z);
                hq.w = f2bf(v.w);
                *(ushort4*)(Ah + i * AS + wq * 4) = hq;
            }
        }
        __syncthreads();

        // ---- GEMM: X[32][64] = A[32][256] @ E[256][64], MFMA 16x16x32 bf16 ----
        {
            const int l  = t & 63, wv = t >> 6;
            const int lr = l & 15, lk = (l >> 4) * 8;
            f32x4 acc0 = {0.f, 0.f, 0.f, 0.f};
            f32x4 acc1 = {0.f, 0.f, 0.f, 0.f};
            const unsigned short* bhp = Eth + (size_t)(wv * 16 + lr) * 256 + lk;
            const unsigned short* blp = Etl + (size_t)(wv * 16 + lr) * 256 + lk;
            const unsigned short* a0p = Ah + lr * AS + lk;
            const unsigned short* a1p = Ah + (16 + lr) * AS + lk;
            #pragma unroll
            for (int ks = 0; ks < 8; ++ks) {
                const int offg = ks * 32;            // global Et stride 256
                const short8 bh = *(const short8*)(bhp + offg);
                const short8 bl = *(const short8*)(blp + offg);
                const short8 a0 = *(const short8*)(a0p + offg);
                const short8 a1 = *(const short8*)(a1p + offg);
                acc0 = __builtin_amdgcn_mfma_f32_16x16x32_bf16(a0, bh, acc0, 0, 0, 0);
                acc1 = __builtin_amdgcn_mfma_f32_16x16x32_bf16(a1, bh, acc1, 0, 0, 0);
                acc0 = __builtin_amdgcn_mfma_f32_16x16x32_bf16(a0, bl, acc0, 0, 0, 0);
                acc1 = __builtin_amdgcn_mfma_f32_16x16x32_bf16(a1, bl, acc1, 0, 0, 0);
            }
            // C/D: col = wv*16 + (lane&15), row = (lane>>4)*4 + reg
            const int col   = wv * 16 + lr;
            const int rbase = (l >> 4) * 4;
            #pragma unroll
            for (int r = 0; r < 4; ++r) {
                const int row0 = rbase + r;
                const int row1 = 16 + rbase + r;
                const float v0 = acc0[r], v1 = acc1[r];
                if (col < 32) {
                    XrL[rr][row0 * 36 + col] = v0;
                    XrL[rr][row1 * 36 + col] = v1;
                } else {
                    XiL[rr][row0 * 36 + col - 32] = v0;
                    XiL[rr][row1 * 36 + col - 32] = v1;
                }
            }
        }
        __syncthreads();
    }

    // ---- phase B: mixW for BOTH rows per weight load; scale folded ----
    {
        const int kq = t & 7, o = t >> 3;
        const int k4 = kq * 4;
        float4 ar0 = {0,0,0,0}, ai0 = {0,0,0,0};
        float4 ar1 = {0,0,0,0}, ai1 = {0,0,0,0};
        const float* wrb = w2r + (size_t)g * 32768 + o * 32 + k4;   // + i*1024
        const float* wib = w2i + (size_t)g * 32768 + o * 32 + k4;
        for (int i = 0; i < 32; ++i) {
            const float4 wr  = *(const float4*)(wrb + i * 1024);
            const float4 wi  = *(const float4*)(wib + i * 1024);
            const float4 xr0 = *(const float4*)(&XrL[0][i * 36 + k4]);
            const float4 xi0 = *(const float4*)(&XiL[0][i * 36 + k4]);
            const float4 xr1 = *(const float4*)(&XrL[1][i * 36 + k4]);
            const float4 xi1 = *(const float4*)(&XiL[1][i * 36 + k4]);
            ar0.x += xr0.x * wr.x - xi0.x * wi.x;  ai0.x += xr0.x * wi.x + xi0.x * wr.x;
            ar0.y += xr0.y * wr.y - xi0.y * wi.y;  ai0.y += xr0.y * wi.y + xi0.y * wr.y;
            ar0.z += xr0.z * wr.z - xi0.z * wi.z;  ai0.z += xr0.z * wi.z + xi0.z * wr.z;
            ar0.w += xr0.w * wr.w - xi0.w * wi.w;  ai0.w += xr0.w * wi.w + xi0.w * wr.w;
            ar1.x += xr1.x * wr.x - xi1.x * wi.x;  ai1.x += xr1.x * wi.x + xi1.x * wr.x;
            ar1.y += xr1.y * wr.y - xi1.y * wi.y;  ai1.y += xr1.y * wi.y + xi1.y * wr.y;
            ar1.z += xr1.z * wr.z - xi1.z * wi.z;  ai1.z += xr1.z * wi.z + xi1.z * wr.z;
            ar1.w += xr1.w * wr.w - xi1.w * wi.w;  ai1.w += xr1.w * wi.w + xi1.w * wr.w;
        }
        const float s2 = 2.f / 256.f, s1 = 1.f / 256.f;
        const float s0 = (k4 == 0) ? s1 : s2;
        float* dst0 = Yw + (size_t)((b * 2 + g) * 32 + o) * 16384
                         + (size_t)(jr * 2) * 64 + k4;
        *(float4*)(dst0)           = make_float4(ar0.x * s0, ar0.y * s2, ar0.z * s2, ar0.w * s2);
        *(float4*)(dst0 + 32)      = make_float4(ai0.x * s0, ai0.y * s2, ai0.z * s2, ai0.w * s2);
        *(float4*)(dst0 + 64)      = make_float4(ar1.x * s0, ar1.y * s2, ar1.z * s2, ar1.w * s2);
        *(float4*)(dst0 + 64 + 32) = make_float4(ai1.x * s0, ai1.y * s2, ai1.z * s2, ai1.w * s2);
    }
}

// ---------------------------------------------------------------------------
// K2: folded DFT_H, SPLIT by slot-half: block = c*2 + shalf (1024 blocks).
// Each block handles 32 of the 64 w-spectral slots of channel c.
// thread map: hs = t&1 (h-half), kg = (t>>1)&15 (2 k's), sp = t>>5 (quad 0..7)
// Z layout: [(bg*32 + kh)*32 + o][128]  (Re_h | Im_h), slots shalf*32+[0,32)
// ---------------------------------------------------------------------------
__global__ __launch_bounds__(256) void h_fwd(const float* __restrict__ Yw,
                                             float* __restrict__ Z) {
    __shared__ float YL[256 * 32];   // 32 KB
    __shared__ float kC[32], kS[32];
    const int bid = blockIdx.x;      // c*2 + shalf
    const int shalf = bid & 1;
    const int cch = bid >> 1;        // channel c = (b*2+g)*32 + o
    const int t = threadIdx.x;
    if (t < 32) {
        float s, c; sincosf(PI2_256 * (float)t, &s, &c);
        kC[t] = c; kS[t] = s;
    }
    {
        const float* src = Yw + (size_t)cch * 16384 + shalf * 32;
        #pragma unroll
        for (int r = 0; r < 8; ++r) {
            const int idx = t + r * 256;            // 0..2047
            const int h = idx >> 3, q = idx & 7;    // 8 quads = 32 floats/row
            *(float4*)(YL + h * 32 + q * 4) =
                *(const float4*)(src + (size_t)h * 64 + q * 4);
        }
    }
    __syncthreads();

    const int hs = t & 1, kg = (t >> 1) & 15, sp = t >> 5;  // sp 0..7
    const int hb = hs * 64;
    const float sgn = (kg & 1) ? -1.f : 1.f;                // (-1)^k, k parity = kg
    const float4 y0q   = *(const float4*)(YL + sp * 4);
    const float4 y128q = *(const float4*)(YL + 128 * 32 + sp * 4);

    float cA[2], sA[2], cB[2], sB[2], t2[2];
    float xr[2][4], xi[2][4];
    #pragma unroll
    for (int kk = 0; kk < 2; ++kk) {
        const int k = kg + 16 * kk;
        const float cd = kC[k], sd = kS[k];
        t2[kk] = 2.f * cd;
        float cA0, sA0;
        if (hs == 0) { cA0 = 1.f; sA0 = 0.f; }              // phasor(0)
        else {                                              // phasor(64k) = i^k
            const int km = k & 3;
            cA0 = (km == 0) ? 1.f : (km == 2) ? -1.f : 0.f;
            sA0 = (km == 1) ? 1.f : (km == 3) ? -1.f : 0.f;
        }
        cA[kk] = cA0; sA[kk] = sA0;
        cB[kk] = cA0 * cd + sA0 * sd;                       // phasor(hb-1)
        sB[kk] = sA0 * cd - cA0 * sd;
        #pragma unroll
        for (int j = 0; j < 4; ++j) {
            xr[kk][j] = (hs == 0) ? (sgn * (&y128q.x)[j] - (&y0q.x)[j]) : 0.f;
            xi[kk][j] = 0.f;
        }
    }
    for (int h = hb; h < hb + 64; ++h) {
        const float4 aq = *(const float4*)(YL + h * 32 + sp * 4);
        const float4 mq = *(const float4*)(YL + ((256 - h) & 255) * 32 + sp * 4);
        float ye[4], yo[4];
        #pragma unroll
        for (int j = 0; j < 4; ++j) {
            ye[j] = (&aq.x)[j] + (&mq.x)[j];
            yo[j] = (&aq.x)[j] - (&mq.x)[j];
        }
        #pragma unroll
        for (int kk = 0; kk < 2; ++kk) {
            #pragma unroll
            for (int j = 0; j < 4; ++j) {
                xr[kk][j] += ye[j] * cA[kk];
                xi[kk][j] -= yo[j] * sA[kk];
            }
            const float cn = t2[kk] * cA[kk] - cB[kk]; cB[kk] = cA[kk]; cA[kk] = cn;
            const float sn = t2[kk] * sA[kk] - sB[kk]; sB[kk] = sA[kk]; sA[kk] = sn;
        }
    }
    // combine h-halves (lane pairs differ in bit 0)
    #pragma unroll
    for (int kk = 0; kk < 2; ++kk)
        #pragma unroll
        for (int j = 0; j < 4; ++j) {
            xr[kk][j] += __shfl_xor(xr[kk][j], 1);
            xi[kk][j] += __shfl_xor(xi[kk][j], 1);
        }
    if (hs == 0) {
        const int o = cch & 31, bg = cch >> 5;
        #pragma unroll
        for (int kk = 0; kk < 2; ++kk) {
            const int k = kg + 16 * kk;
            const size_t zi_ = (((size_t)bg * 32 + k) * 32 + o) * 128
                             + shalf * 32 + sp * 4;
            *(float4*)(Z + zi_)      = make_float4(xr[kk][0], xr[kk][1], xr[kk][2], xr[kk][3]);
            *(float4*)(Z + zi_ + 64) = make_float4(xi[kk][0], xi[kk][1], xi[kk][2], xi[kk][3]);
        }
    }
}

// ---------------------------------------------------------------------------
// K3: mixH per (b,g,kh); H-ortho scale folded. Z2: [(bg*32+o)*32+kh][128]
// ---------------------------------------------------------------------------
__global__ __launch_bounds__(256) void h_mix2(const float* __restrict__ Z,
                                              const float* __restrict__ w1r,
                                              const float* __restrict__ w1i,
                                              float* __restrict__ Z2) {
    __shared__ float ZL[32 * 128];          // [i][128] 16 KB
    __shared__ float WrL[1024], WiL[1024];  // [i*32+o] 8 KB
    const int bid = blockIdx.x;             // bg*32 + kh
    const int kh = bid & 31, bg = bid >> 5;
    const int g = bg & 1;
    const int t = threadIdx.x;
    {
        const float* src = Z + (size_t)bid * 4096;
        #pragma unroll
        for (int r = 0; r < 4; ++r) {
            const int f = t + r * 256;
            *(float4*)(ZL + f * 4) = *(const float4*)(src + f * 4);
        }
        #pragma unroll
        for (int r = 0; r < 4; ++r) {
            const int idx = t + r * 256;    // i = idx>>5, o = idx&31
            const int gidx = g * 32768 + (idx >> 5) * 1024 + (idx & 31) * 32 + kh;
            WrL[idx] = w1r[gidx];
            WiL[idx] = w1i[gidx];
        }
    }
    __syncthreads();

    const int s = t & 63, og = t >> 6;      // o = og*8 + m
    float accr[8], acci[8];
    #pragma unroll
    for (int m = 0; m < 8; ++m) { accr[m] = 0.f; acci[m] = 0.f; }
    for (int i = 0; i < 32; ++i) {
        const float zr = ZL[i * 128 + s];
        const float zi = ZL[i * 128 + 64 + s];
        #pragma unroll
        for (int m = 0; m < 8; ++m) {
            const int o = og * 8 + m;
            const float wr = WrL[i * 32 + o];
            const float wi = WiL[i * 32 + o];
            accr[m] += zr * wr - zi * wi;
            acci[m] += zr * wi + zi * wr;
        }
    }
    const float sck = (kh == 0) ? (1.f / 256.f) : (2.f / 256.f);
    #pragma unroll
    for (int m = 0; m < 8; ++m) {
        const int o = og * 8 + m;
        const size_t zo = ((size_t)(bg * 32 + o) * 32 + kh) * 128 + s;
        Z2[zo]      = accr[m] * sck;
        Z2[zo + 64] = acci[m] * sck;
    }
}

// ---------------------------------------------------------------------------
// K4: IDFT_H (mirror, Nyquist) per channel c. Trig staged in LDS.
// ---------------------------------------------------------------------------
__global__ __launch_bounds__(256) void h_inv2(const float* __restrict__ Z2,
                                              const float* __restrict__ tc,
                                              const float* __restrict__ ts,
                                              float* __restrict__ YHg) {
    __shared__ float ZL[32 * 128];                  // 16 KB
    __shared__ float TcL[32 * 128], TsL[32 * 128];  // 16+16 KB (lower-half trig)
    const int bid = blockIdx.x;                     // channel c
    const int t = threadIdx.x;
    {
        const float* src = Z2 + (size_t)bid * 4096;
        #pragma unroll
        for (int r = 0; r < 4; ++r) {
            const int f = t + r * 256;
            *(float4*)(ZL + f * 4) = *(const float4*)(src + f * 4);
        }
        #pragma unroll
        for (int r = 0; r < 4; ++r) {
            const int q = t + r * 256;              // 0..1023
            const int k = q >> 5, hq = q & 31;
            *(float4*)(TcL + k * 128 + hq * 4) = *(const float4*)(tc + (size_t)k * 256 + hq * 4);
            *(float4*)(TsL + k * 128 + hq * 4) = *(const float4*)(ts + (size_t)k * 256 + hq * 4);
        }
    }
    __syncthreads();

    const int s = t & 63, hg = t >> 6;              // hg 0..3
    float zr[32], zi[32];
    #pragma unroll
    for (int k = 0; k < 32; ++k) {
        zr[k] = ZL[k * 128 + s];
        zi[k] = ZL[k * 128 + 64 + s];
    }
    float* dst = YHg + (size_t)bid * 16384;
    #pragma unroll
    for (int jq = 0; jq < 8; ++jq) {
        const int h0 = hg * 32 + jq * 4;            // 0..124
        float sC[4] = {0, 0, 0, 0}, sS[4] = {0, 0, 0, 0};
        #pragma unroll
        for (int k = 0; k < 32; ++k) {
            const float4 c4 = *(const float4*)(TcL + k * 128 + h0);  // wave-uniform
            const float4 s4 = *(const float4*)(TsL + k * 128 + h0);
            sC[0] += zr[k] * c4.x;  sS[0] += zi[k] * s4.x;
            sC[1] += zr[k] * c4.y;  sS[1] += zi[k] * s4.y;
            sC[2] += zr[k] * c4.z;  sS[2] += zi[k] * s4.z;
            sC[3] += zr[k] * c4.w;  sS[3] += zi[k] * s4.w;
        }
        #pragma unroll
        for (int jj = 0; jj < 4; ++jj) {
            const int h = h0 + jj;
            dst[h * 64 + s] = sC[jj] - sS[jj];
            if (h > 0) dst[(256 - h) * 64 + s] = sC[jj] + sS[jj];
        }
    }
    if (hg == 0) {                                  // Nyquist row h = 128
        float ny = 0.f;
        #pragma unroll
        for (int k = 0; k < 32; ++k) ny += (k & 1) ? -zr[k] : zr[k];
        dst[128 * 64 + s] = ny;
    }
}

// ---------------------------------------------------------------------------
// K5: IDFT_W (mirror, Nyquist). block = (c, hb): 32 h-rows. Trig in LDS.
// Mirror half assembled via width-32 shuffles -> ALL stores are float4.
// ---------------------------------------------------------------------------
__global__ __launch_bounds__(256) void w_inv2(const float* __restrict__ YHg,
                                              const float* __restrict__ tc,
                                              const float* __restrict__ ts,
                                              float* __restrict__ out) {
    __shared__ float YL[32 * 64];                   // 8 KB  [hl][64]
    __shared__ float TcL[32 * 128], TsL[32 * 128];  // 32 KB (lower-half trig)
    const int bid = blockIdx.x;
    const int hb = bid & 7, c = bid >> 3;
    const int t = threadIdx.x;
    {
        const float* src = YHg + (size_t)c * 16384 + hb * 2048;
        #pragma unroll
        for (int r = 0; r < 2; ++r) {
            const int f = t + r * 256;
            *(float4*)(YL + f * 4) = *(const float4*)(src + f * 4);
        }
        #pragma unroll
        for (int r = 0; r < 4; ++r) {
            const int q = t + r * 256;              // 0..1023
            const int k = q >> 5, wq_ = q & 31;
            *(float4*)(TcL + k * 128 + wq_ * 4) = *(const float4*)(tc + (size_t)k * 256 + wq_ * 4);
            *(float4*)(TsL + k * 128 + wq_ * 4) = *(const float4*)(ts + (size_t)k * 256 + wq_ * 4);
        }
    }
    __syncthreads();

    const int wq = t & 31, hh = t >> 5;             // 4 h-rows per thread
    const int w0 = wq * 4;
    float* outp = out + (size_t)c * 65536;

    float sC[4][4], sS[4][4];                       // [j][w-lane]
    float nyA[4];                                   // Nyquist accum (uniform per row)
    #pragma unroll
    for (int j = 0; j < 4; ++j) {
        nyA[j] = 0.f;
        #pragma unroll
        for (int jj = 0; jj < 4; ++jj) { sC[j][jj] = 0.f; sS[j][jj] = 0.f; }
    }

    for (int k = 0; k < 32; ++k) {
        const float4 c4 = *(const float4*)(TcL + k * 128 + w0);
        const float4 s4 = *(const float4*)(TsL + k * 128 + w0);
        const float sk = (k & 1) ? -1.f : 1.f;
        #pragma unroll
        for (int j = 0; j < 4; ++j) {
            const int hl = hh * 4 + j;
            const float R = YL[hl * 64 + k];
            const float I = YL[hl * 64 + 32 + k];
            nyA[j] += sk * R;
            sC[j][0] += R * c4.x;  sS[j][0] += I * s4.x;
            sC[j][1] += R * c4.y;  sS[j][1] += I * s4.y;
            sC[j][2] += R * c4.z;  sS[j][2] += I * s4.z;
            sC[j][3] += R * c4.w;  sS[j][3] += I * s4.w;
        }
    }
    #pragma unroll
    for (int j = 0; j < 4; ++j) {
        const int h = hb * 32 + hh * 4 + j;
        *(float4*)(outp + (size_t)h * 256 + w0) =
            make_float4(sC[j][0] - sS[j][0], sC[j][1] - sS[j][1],
                        sC[j][2] - sS[j][2], sC[j][3] - sS[j][3]);
        const float p0 = sC[j][0] + sS[j][0];
        const float p1 = sC[j][1] + sS[j][1];
        const float p2 = sC[j][2] + sS[j][2];
        const float p3 = sC[j][3] + sS[j][3];
        const float m0s = __shfl(p0, 32 - wq, 32);
        const float m0  = (wq == 0) ? nyA[j] : m0s;
        const float m1  = __shfl(p3, 31 - wq, 32);
        const float m2  = __shfl(p2, 31 - wq, 32);
        const float m3  = __shfl(p1, 31 - wq, 32);
        *(float4*)(outp + (size_t)h * 256 + 128 + w0) = make_float4(m0, m1, m2, m3);
    }
}

// ---------------------------------------------------------------------------
extern "C" void kernel_launch(void* const* d_in, const int* in_sizes, int n_in,
                              void* d_out, int out_size, void* d_ws, size_t ws_size,
                              hipStream_t stream) {
    const float* x   = (const float*)d_in[0];
    const float* w1r = (const float*)d_in[1];
    const float* w1i = (const float*)d_in[2];
    const float* w2r = (const float*)d_in[3];
    const float* w2i = (const float*)d_in[4];
    float* out = (float*)d_out;
    float* ws  = (float*)d_ws;

    float* tc = ws;                    //  8192 floats
    float* ts = ws + 8192;             //  8192 floats
    float* Yw = ws + 16384;            //  8,388,608 floats (33.5 MB) — reused as YHg
    float* Z  = Yw + 8388608;          //  2,097,152 floats ( 8.4 MB)
    float* Z2 = Z + 2097152;           //  2,097,152 floats ( 8.4 MB)
    unsigned short* Eth = (unsigned short*)(Z2 + 2097152);   // 16384 bf16 (32 KB)
    unsigned short* Etl = Eth + 16384;                       // 16384 bf16 (32 KB)

    init_tab<<<32, 256, 0, stream>>>(tc, ts);
    init_et<<<64, 256, 0, stream>>>(Eth, Etl);
    w_fwd<<<2048, 256, 0, stream>>>(x, w2r, w2i, Eth, Etl, Yw);
    h_fwd<<<1024, 256, 0, stream>>>(Yw, Z);
    h_mix2<<<512, 256, 0, stream>>>(Z, w1r, w1i, Z2);
    h_inv2<<<512, 256, 0, stream>>>(Z2, tc, ts, Yw);   // Yw region reused as YH
    w_inv2<<<4096, 256, 0, stream>>>(Yw, tc, ts, out);
}

// Round 22
// 176.443 us; speedup vs baseline: 1.3042x; 1.0433x over previous
//
#include <hip/hip_runtime.h>
#include <math.h>

// x: [8][64][256][256] f32 ; w1/w2: [2][32][32][32] f32 (re,im separate)
// Pipeline (best configuration, R17):
//   K1 w_fwd : DFT_W via MFMA, x in bf16 (RNE), E in bf16 hi+lo -> Yw[c][h][64]
//   K2 h_fwd : DFT_H (folded, Chebyshev)  -> Z [bg,kh,o][128]
//   K3 h_mix2: mixH                       -> Z2[c][kh][128]
//   K4 h_inv2: IDFT_H (mirror)            -> YH[c][h][64] (reuses Yw region)
//   K5 w_inv2: IDFT_W (mirror)            -> out (all-float4 stores via shfl)
#define PI2_256 0.0245436926061702596754894014318f  // 2*pi/256
#define AS 264   // padded bf16 tile stride: 528B = 16B mod 128B -> conflict-free b128

typedef __attribute__((ext_vector_type(8))) short short8;   // 8 bf16 (4 VGPRs)
typedef __attribute__((ext_vector_type(4))) float f32x4;

static __device__ __forceinline__ unsigned short f2bf(float f) {
    unsigned int u = __float_as_uint(f);
    u = (u + 0x7FFFu + ((u >> 16) & 1u)) >> 16;              // RNE
    return (unsigned short)u;
}
static __device__ __forceinline__ float bf2f(unsigned short h) {
    return __uint_as_float(((unsigned int)h) << 16);
}

// ---------------------------------------------------------------------------
__global__ __launch_bounds__(256) void init_tab(float* __restrict__ tc, float* __restrict__ ts) {
    int idx = blockIdx.x * 256 + threadIdx.x;   // 0..8191
    int k = idx >> 8, n = idx & 255;            // k < 32
    int m = (k * n) & 255;
    float s, c;
    sincosf(PI2_256 * (float)m, &s, &c);
    tc[idx] = c;
    ts[idx] = s;
}

// Et (transposed DFT matrix) in bf16 hi/lo: Et[n][w], n<32: cos(2pi n w/256),
// n in 32..63: -sin(2pi (n-32) w/256).
__global__ __launch_bounds__(256) void init_et(unsigned short* __restrict__ Eth,
                                               unsigned short* __restrict__ Etl) {
    int idx = blockIdx.x * 256 + threadIdx.x;   // 0..16383
    int n = idx >> 8, w = idx & 255;
    int k = n & 31;
    int m = (k * w) & 255;
    float s, c;
    sincosf(PI2_256 * (float)m, &s, &c);
    float v = (n < 32) ? c : -s;
    unsigned short h = f2bf(v);
    Eth[idx] = h;
    Etl[idx] = f2bf(v - bf2f(h));
}

// ---------------------------------------------------------------------------
// K1: per block = (b,g,row-pair). Per row: stage x->bf16 (padded) -> MFMA
// GEMM X = x @ E (x_hi * (E_hi + E_lo), fp32 acc) -> XrL[rr]. One phase B.
// ---------------------------------------------------------------------------
__global__ __launch_bounds__(256) void w_fwd(const float* __restrict__ x,
                                             const float* __restrict__ w2r,
                                             const float* __restrict__ w2i,
                                             const unsigned short* __restrict__ Eth,
                                             const unsigned short* __restrict__ Etl,
                                             float* __restrict__ Yw) {
    __shared__ __attribute__((aligned(16))) unsigned short Ah[32 * AS];   // 16.5 KB
    __shared__ float XrL[2][32 * 36], XiL[2][32 * 36];                    // 18.4 KB

    const int bid = blockIdx.x;      // 2048 blocks
    const int jr  = bid & 127;       // row pair
    const int g   = (bid >> 7) & 1;
    const int b   = bid >> 8;
    const int t   = threadIdx.x;

    const size_t chan0 = (size_t)(b * 64 + g * 32);

    for (int rr = 0; rr < 2; ++rr) {
        const int xrow = jr * 2 + rr;
        const size_t base = (chan0 * 256 + xrow) * 256;    // + i*65536 + w

        // ---- stage + convert to bf16 (padded stride) ----
        {
            const int wq = t & 63, i0 = t >> 6;
            #pragma unroll
            for (int r = 0; r < 8; ++r) {
                const int i = i0 + r * 4;
                const float4 v = *(const float4*)(x + base + (size_t)i * 65536 + wq * 4);
                ushort4 hq;
                hq.x = f2bf(v.x);
                hq.y = f2bf(v.y);
                hq.z = f2bf(v.z);
                hq.w = f2bf(v.w);
                *(ushort4*)(Ah + i * AS + wq * 4) = hq;
            }
        }
        __syncthreads();

        // ---- GEMM: X[32][64] = A[32][256] @ E[256][64], MFMA 16x16x32 bf16 ----
        {
            const int l  = t & 63, wv = t >> 6;
            const int lr = l & 15, lk = (l >> 4) * 8;
            f32x4 acc0 = {0.f, 0.f, 0.f, 0.f};
            f32x4 acc1 = {0.f, 0.f, 0.f, 0.f};
            const unsigned short* bhp = Eth + (size_t)(wv * 16 + lr) * 256 + lk;
            const unsigned short* blp = Etl + (size_t)(wv * 16 + lr) * 256 + lk;
            const unsigned short* a0p = Ah + lr * AS + lk;
            const unsigned short* a1p = Ah + (16 + lr) * AS + lk;
            #pragma unroll
            for (int ks = 0; ks < 8; ++ks) {
                const int offg = ks * 32;            // global Et stride 256
                const short8 bh = *(const short8*)(bhp + offg);
                const short8 bl = *(const short8*)(blp + offg);
                const short8 a0 = *(const short8*)(a0p + offg);
                const short8 a1 = *(const short8*)(a1p + offg);
                acc0 = __builtin_amdgcn_mfma_f32_16x16x32_bf16(a0, bh, acc0, 0, 0, 0);
                acc1 = __builtin_amdgcn_mfma_f32_16x16x32_bf16(a1, bh, acc1, 0, 0, 0);
                acc0 = __builtin_amdgcn_mfma_f32_16x16x32_bf16(a0, bl, acc0, 0, 0, 0);
                acc1 = __builtin_amdgcn_mfma_f32_16x16x32_bf16(a1, bl, acc1, 0, 0, 0);
            }
            // C/D: col = wv*16 + (lane&15), row = (lane>>4)*4 + reg
            const int col   = wv * 16 + lr;
            const int rbase = (l >> 4) * 4;
            #pragma unroll
            for (int r = 0; r < 4; ++r) {
                const int row0 = rbase + r;
                const int row1 = 16 + rbase + r;
                const float v0 = acc0[r], v1 = acc1[r];
                if (col < 32) {
                    XrL[rr][row0 * 36 + col] = v0;
                    XrL[rr][row1 * 36 + col] = v1;
                } else {
                    XiL[rr][row0 * 36 + col - 32] = v0;
                    XiL[rr][row1 * 36 + col - 32] = v1;
                }
            }
        }
        __syncthreads();
    }

    // ---- phase B: mixW for BOTH rows per weight load; scale folded ----
    {
        const int kq = t & 7, o = t >> 3;
        const int k4 = kq * 4;
        float4 ar0 = {0,0,0,0}, ai0 = {0,0,0,0};
        float4 ar1 = {0,0,0,0}, ai1 = {0,0,0,0};
        const float* wrb = w2r + (size_t)g * 32768 + o * 32 + k4;   // + i*1024
        const float* wib = w2i + (size_t)g * 32768 + o * 32 + k4;
        for (int i = 0; i < 32; ++i) {
            const float4 wr  = *(const float4*)(wrb + i * 1024);
            const float4 wi  = *(const float4*)(wib + i * 1024);
            const float4 xr0 = *(const float4*)(&XrL[0][i * 36 + k4]);
            const float4 xi0 = *(const float4*)(&XiL[0][i * 36 + k4]);
            const float4 xr1 = *(const float4*)(&XrL[1][i * 36 + k4]);
            const float4 xi1 = *(const float4*)(&XiL[1][i * 36 + k4]);
            ar0.x += xr0.x * wr.x - xi0.x * wi.x;  ai0.x += xr0.x * wi.x + xi0.x * wr.x;
            ar0.y += xr0.y * wr.y - xi0.y * wi.y;  ai0.y += xr0.y * wi.y + xi0.y * wr.y;
            ar0.z += xr0.z * wr.z - xi0.z * wi.z;  ai0.z += xr0.z * wi.z + xi0.z * wr.z;
            ar0.w += xr0.w * wr.w - xi0.w * wi.w;  ai0.w += xr0.w * wi.w + xi0.w * wr.w;
            ar1.x += xr1.x * wr.x - xi1.x * wi.x;  ai1.x += xr1.x * wi.x + xi1.x * wr.x;
            ar1.y += xr1.y * wr.y - xi1.y * wi.y;  ai1.y += xr1.y * wi.y + xi1.y * wr.y;
            ar1.z += xr1.z * wr.z - xi1.z * wi.z;  ai1.z += xr1.z * wi.z + xi1.z * wr.z;
            ar1.w += xr1.w * wr.w - xi1.w * wi.w;  ai1.w += xr1.w * wi.w + xi1.w * wr.w;
        }
        const float s2 = 2.f / 256.f, s1 = 1.f / 256.f;
        const float s0 = (k4 == 0) ? s1 : s2;
        float* dst0 = Yw + (size_t)((b * 2 + g) * 32 + o) * 16384
                         + (size_t)(jr * 2) * 64 + k4;
        *(float4*)(dst0)           = make_float4(ar0.x * s0, ar0.y * s2, ar0.z * s2, ar0.w * s2);
        *(float4*)(dst0 + 32)      = make_float4(ai0.x * s0, ai0.y * s2, ai0.z * s2, ai0.w * s2);
        *(float4*)(dst0 + 64)      = make_float4(ar1.x * s0, ar1.y * s2, ar1.z * s2, ar1.w * s2);
        *(float4*)(dst0 + 64 + 32) = make_float4(ai1.x * s0, ai1.y * s2, ai1.z * s2, ai1.w * s2);
    }
}

// ---------------------------------------------------------------------------
// K2: folded DFT_H per channel c. Chebyshev with exact LDS-derived seeds.
// ---------------------------------------------------------------------------
__global__ __launch_bounds__(256) void h_fwd(const float* __restrict__ Yw,
                                             float* __restrict__ Z) {
    __shared__ float YL[256 * 64];   // 64 KB
    __shared__ float kC[32], kS[32];
    const int bid = blockIdx.x;      // (b*2+g)*32 + o
    const int t = threadIdx.x;
    if (t < 32) {
        float s, c; sincosf(PI2_256 * (float)t, &s, &c);
        kC[t] = c; kS[t] = s;
    }
    {
        const float* src = Yw + (size_t)bid * 16384;
        #pragma unroll
        for (int r = 0; r < 16; ++r) {
            const int f = t + r * 256;
            *(float4*)(YL + f * 4) = *(const float4*)(src + f * 4);
        }
    }
    __syncthreads();

    const int hs = t & 1, kg = (t >> 1) & 7, sp = t >> 4;  // slots 4sp..4sp+3
    const int hb = hs * 64;
    const float sgn = (kg & 1) ? -1.f : 1.f;
    const float4 y0q   = *(const float4*)(YL + sp * 4);
    const float4 y128q = *(const float4*)(YL + 128 * 64 + sp * 4);

    float cA[4], sA[4], cB[4], sB[4], t2[4];
    float xr[4][4], xi[4][4];
    #pragma unroll
    for (int kk = 0; kk < 4; ++kk) {
        const int k = kg + 8 * kk;
        const float cd = kC[k], sd = kS[k];
        t2[kk] = 2.f * cd;
        float cA0, sA0;
        if (hs == 0) { cA0 = 1.f; sA0 = 0.f; }
        else {
            const int km = k & 3;
            cA0 = (km == 0) ? 1.f : (km == 2) ? -1.f : 0.f;
            sA0 = (km == 1) ? 1.f : (km == 3) ? -1.f : 0.f;
        }
        cA[kk] = cA0; sA[kk] = sA0;
        cB[kk] = cA0 * cd + sA0 * sd;
        sB[kk] = sA0 * cd - cA0 * sd;
        #pragma unroll
        for (int j = 0; j < 4; ++j) {
            xr[kk][j] = (hs == 0) ? (sgn * (&y128q.x)[j] - (&y0q.x)[j]) : 0.f;
            xi[kk][j] = 0.f;
        }
    }
    for (int h = hb; h < hb + 64; ++h) {
        const float4 aq = *(const float4*)(YL + h * 64 + sp * 4);
        const float4 mq = *(const float4*)(YL + ((256 - h) & 255) * 64 + sp * 4);
        float ye[4], yo[4];
        #pragma unroll
        for (int j = 0; j < 4; ++j) {
            ye[j] = (&aq.x)[j] + (&mq.x)[j];
            yo[j] = (&aq.x)[j] - (&mq.x)[j];
        }
        #pragma unroll
        for (int kk = 0; kk < 4; ++kk) {
            #pragma unroll
            for (int j = 0; j < 4; ++j) {
                xr[kk][j] += ye[j] * cA[kk];
                xi[kk][j] -= yo[j] * sA[kk];
            }
            const float cn = t2[kk] * cA[kk] - cB[kk]; cB[kk] = cA[kk]; cA[kk] = cn;
            const float sn = t2[kk] * sA[kk] - sB[kk]; sB[kk] = sA[kk]; sA[kk] = sn;
        }
    }
    #pragma unroll
    for (int kk = 0; kk < 4; ++kk)
        #pragma unroll
        for (int j = 0; j < 4; ++j) {
            xr[kk][j] += __shfl_xor(xr[kk][j], 1);
            xi[kk][j] += __shfl_xor(xi[kk][j], 1);
        }
    if (hs == 0) {
        const int o = bid & 31, bg = bid >> 5;
        #pragma unroll
        for (int kk = 0; kk < 4; ++kk) {
            const int k = kg + 8 * kk;
            const size_t zi_ = (((size_t)bg * 32 + k) * 32 + o) * 128 + sp * 4;
            *(float4*)(Z + zi_)      = make_float4(xr[kk][0], xr[kk][1], xr[kk][2], xr[kk][3]);
            *(float4*)(Z + zi_ + 64) = make_float4(xi[kk][0], xi[kk][1], xi[kk][2], xi[kk][3]);
        }
    }
}

// ---------------------------------------------------------------------------
// K3: mixH per (b,g,kh); H-ortho scale folded. Z2: [(bg*32+o)*32+kh][128]
// ---------------------------------------------------------------------------
__global__ __launch_bounds__(256) void h_mix2(const float* __restrict__ Z,
                                              const float* __restrict__ w1r,
                                              const float* __restrict__ w1i,
                                              float* __restrict__ Z2) {
    __shared__ float ZL[32 * 128];          // [i][128] 16 KB
    __shared__ float WrL[1024], WiL[1024];  // [i*32+o] 8 KB
    const int bid = blockIdx.x;             // bg*32 + kh
    const int kh = bid & 31, bg = bid >> 5;
    const int g = bg & 1;
    const int t = threadIdx.x;
    {
        const float* src = Z + (size_t)bid * 4096;
        #pragma unroll
        for (int r = 0; r < 4; ++r) {
            const int f = t + r * 256;
            *(float4*)(ZL + f * 4) = *(const float4*)(src + f * 4);
        }
        #pragma unroll
        for (int r = 0; r < 4; ++r) {
            const int idx = t + r * 256;    // i = idx>>5, o = idx&31
            const int gidx = g * 32768 + (idx >> 5) * 1024 + (idx & 31) * 32 + kh;
            WrL[idx] = w1r[gidx];
            WiL[idx] = w1i[gidx];
        }
    }
    __syncthreads();

    const int s = t & 63, og = t >> 6;      // o = og*8 + m
    float accr[8], acci[8];
    #pragma unroll
    for (int m = 0; m < 8; ++m) { accr[m] = 0.f; acci[m] = 0.f; }
    for (int i = 0; i < 32; ++i) {
        const float zr = ZL[i * 128 + s];
        const float zi = ZL[i * 128 + 64 + s];
        #pragma unroll
        for (int m = 0; m < 8; ++m) {
            const int o = og * 8 + m;
            const float wr = WrL[i * 32 + o];
            const float wi = WiL[i * 32 + o];
            accr[m] += zr * wr - zi * wi;
            acci[m] += zr * wi + zi * wr;
        }
    }
    const float sck = (kh == 0) ? (1.f / 256.f) : (2.f / 256.f);
    #pragma unroll
    for (int m = 0; m < 8; ++m) {
        const int o = og * 8 + m;
        const size_t zo = ((size_t)(bg * 32 + o) * 32 + kh) * 128 + s;
        Z2[zo]      = accr[m] * sck;
        Z2[zo + 64] = acci[m] * sck;
    }
}

// ---------------------------------------------------------------------------
// K4: IDFT_H (mirror, Nyquist) per channel c. Trig staged in LDS.
// ---------------------------------------------------------------------------
__global__ __launch_bounds__(256) void h_inv2(const float* __restrict__ Z2,
                                              const float* __restrict__ tc,
                                              const float* __restrict__ ts,
                                              float* __restrict__ YHg) {
    __shared__ float ZL[32 * 128];                  // 16 KB
    __shared__ float TcL[32 * 128], TsL[32 * 128];  // 16+16 KB (lower-half trig)
    const int bid = blockIdx.x;                     // channel c
    const int t = threadIdx.x;
    {
        const float* src = Z2 + (size_t)bid * 4096;
        #pragma unroll
        for (int r = 0; r < 4; ++r) {
            const int f = t + r * 256;
            *(float4*)(ZL + f * 4) = *(const float4*)(src + f * 4);
        }
        #pragma unroll
        for (int r = 0; r < 4; ++r) {
            const int q = t + r * 256;              // 0..1023
            const int k = q >> 5, hq = q & 31;
            *(float4*)(TcL + k * 128 + hq * 4) = *(const float4*)(tc + (size_t)k * 256 + hq * 4);
            *(float4*)(TsL + k * 128 + hq * 4) = *(const float4*)(ts + (size_t)k * 256 + hq * 4);
        }
    }
    __syncthreads();

    const int s = t & 63, hg = t >> 6;              // hg 0..3
    float zr[32], zi[32];
    #pragma unroll
    for (int k = 0; k < 32; ++k) {
        zr[k] = ZL[k * 128 + s];
        zi[k] = ZL[k * 128 + 64 + s];
    }
    float* dst = YHg + (size_t)bid * 16384;
    #pragma unroll
    for (int jq = 0; jq < 8; ++jq) {
        const int h0 = hg * 32 + jq * 4;            // 0..124
        float sC[4] = {0, 0, 0, 0}, sS[4] = {0, 0, 0, 0};
        #pragma unroll
        for (int k = 0; k < 32; ++k) {
            const float4 c4 = *(const float4*)(TcL + k * 128 + h0);  // wave-uniform
            const float4 s4 = *(const float4*)(TsL + k * 128 + h0);
            sC[0] += zr[k] * c4.x;  sS[0] += zi[k] * s4.x;
            sC[1] += zr[k] * c4.y;  sS[1] += zi[k] * s4.y;
            sC[2] += zr[k] * c4.z;  sS[2] += zi[k] * s4.z;
            sC[3] += zr[k] * c4.w;  sS[3] += zi[k] * s4.w;
        }
        #pragma unroll
        for (int jj = 0; jj < 4; ++jj) {
            const int h = h0 + jj;
            dst[h * 64 + s] = sC[jj] - sS[jj];
            if (h > 0) dst[(256 - h) * 64 + s] = sC[jj] + sS[jj];
        }
    }
    if (hg == 0) {                                  // Nyquist row h = 128
        float ny = 0.f;
        #pragma unroll
        for (int k = 0; k < 32; ++k) ny += (k & 1) ? -zr[k] : zr[k];
        dst[128 * 64 + s] = ny;
    }
}

// ---------------------------------------------------------------------------
// K5: IDFT_W (mirror, Nyquist). block = (c, hb): 32 h-rows. Trig in LDS.
// Mirror half assembled via width-32 shuffles -> ALL stores are float4.
// ---------------------------------------------------------------------------
__global__ __launch_bounds__(256) void w_inv2(const float* __restrict__ YHg,
                                              const float* __restrict__ tc,
                                              const float* __restrict__ ts,
                                              float* __restrict__ out) {
    __shared__ float YL[32 * 64];                   // 8 KB  [hl][64]
    __shared__ float TcL[32 * 128], TsL[32 * 128];  // 32 KB (lower-half trig)
    const int bid = blockIdx.x;
    const int hb = bid & 7, c = bid >> 3;
    const int t = threadIdx.x;
    {
        const float* src = YHg + (size_t)c * 16384 + hb * 2048;
        #pragma unroll
        for (int r = 0; r < 2; ++r) {
            const int f = t + r * 256;
            *(float4*)(YL + f * 4) = *(const float4*)(src + f * 4);
        }
        #pragma unroll
        for (int r = 0; r < 4; ++r) {
            const int q = t + r * 256;              // 0..1023
            const int k = q >> 5, wq_ = q & 31;
            *(float4*)(TcL + k * 128 + wq_ * 4) = *(const float4*)(tc + (size_t)k * 256 + wq_ * 4);
            *(float4*)(TsL + k * 128 + wq_ * 4) = *(const float4*)(ts + (size_t)k * 256 + wq_ * 4);
        }
    }
    __syncthreads();

    const int wq = t & 31, hh = t >> 5;             // 4 h-rows per thread
    const int w0 = wq * 4;
    float* outp = out + (size_t)c * 65536;

    float sC[4][4], sS[4][4];                       // [j][w-lane]
    float nyA[4];                                   // Nyquist accum (uniform per row)
    #pragma unroll
    for (int j = 0; j < 4; ++j) {
        nyA[j] = 0.f;
        #pragma unroll
        for (int jj = 0; jj < 4; ++jj) { sC[j][jj] = 0.f; sS[j][jj] = 0.f; }
    }

    for (int k = 0; k < 32; ++k) {
        const float4 c4 = *(const float4*)(TcL + k * 128 + w0);
        const float4 s4 = *(const float4*)(TsL + k * 128 + w0);
        const float sk = (k & 1) ? -1.f : 1.f;
        #pragma unroll
        for (int j = 0; j < 4; ++j) {
            const int hl = hh * 4 + j;
            const float R = YL[hl * 64 + k];
            const float I = YL[hl * 64 + 32 + k];
            nyA[j] += sk * R;
            sC[j][0] += R * c4.x;  sS[j][0] += I * s4.x;
            sC[j][1] += R * c4.y;  sS[j][1] += I * s4.y;
            sC[j][2] += R * c4.z;  sS[j][2] += I * s4.z;
            sC[j][3] += R * c4.w;  sS[j][3] += I * s4.w;
        }
    }
    #pragma unroll
    for (int j = 0; j < 4; ++j) {
        const int h = hb * 32 + hh * 4 + j;
        *(float4*)(outp + (size_t)h * 256 + w0) =
            make_float4(sC[j][0] - sS[j][0], sC[j][1] - sS[j][1],
                        sC[j][2] - sS[j][2], sC[j][3] - sS[j][3]);
        const float p0 = sC[j][0] + sS[j][0];
        const float p1 = sC[j][1] + sS[j][1];
        const float p2 = sC[j][2] + sS[j][2];
        const float p3 = sC[j][3] + sS[j][3];
        const float m0s = __shfl(p0, 32 - wq, 32);
        const float m0  = (wq == 0) ? nyA[j] : m0s;
        const float m1  = __shfl(p3, 31 - wq, 32);
        const float m2  = __shfl(p2, 31 - wq, 32);
        const float m3  = __shfl(p1, 31 - wq, 32);
        *(float4*)(outp + (size_t)h * 256 + 128 + w0) = make_float4(m0, m1, m2, m3);
    }
}

// ---------------------------------------------------------------------------
extern "C" void kernel_launch(void* const* d_in, const int* in_sizes, int n_in,
                              void* d_out, int out_size, void* d_ws, size_t ws_size,
                              hipStream_t stream) {
    const float* x   = (const float*)d_in[0];
    const float* w1r = (const float*)d_in[1];
    const float* w1i = (const float*)d_in[2];
    const float* w2r = (const float*)d_in[3];
    const float* w2i = (const float*)d_in[4];
    float* out = (float*)d_out;
    float* ws  = (float*)d_ws;

    float* tc = ws;                    //  8192 floats
    float* ts = ws + 8192;             //  8192 floats
    float* Yw = ws + 16384;            //  8,388,608 floats (33.5 MB) — reused as YHg
    float* Z  = Yw + 8388608;          //  2,097,152 floats ( 8.4 MB)
    float* Z2 = Z + 2097152;           //  2,097,152 floats ( 8.4 MB)
    unsigned short* Eth = (unsigned short*)(Z2 + 2097152);   // 16384 bf16 (32 KB)
    unsigned short* Etl = Eth + 16384;                       // 16384 bf16 (32 KB)

    init_tab<<<32, 256, 0, stream>>>(tc, ts);
    init_et<<<64, 256, 0, stream>>>(Eth, Etl);
    w_fwd<<<2048, 256, 0, stream>>>(x, w2r, w2i, Eth, Etl, Yw);
    h_fwd<<<512, 256, 0, stream>>>(Yw, Z);
    h_mix2<<<512, 256, 0, stream>>>(Z, w1r, w1i, Z2);
    h_inv2<<<512, 256, 0, stream>>>(Z2, tc, ts, Yw);   // Yw region reused as YH
    w_inv2<<<4096, 256, 0, stream>>>(Yw, tc, ts, out);
}